// Round 5
// baseline (448.951 us; speedup 1.0000x reference)
//
#include <hip/hip_runtime.h>
#include <math.h>

#define N_TOK   65536
#define DIM     128
#define KCODE   1024

// ---- d_out element offsets ----
#define OUT_QUANT_OFF 1
#define OUT_PERP_OFF  8388609
#define OUT_ENC_OFF   8388610

// ---- workspace byte offsets ----
#define WS_SE64     0            // 1024 * 8
#define WS_SE32     8192         // 1024 * 4
#define WS_IDX      12288        // 65536 * 4        -> 274432
#define WS_FLAGLIST 274432       // 65536 * 4        -> 536576
#define WS_FLAGCNT  536576       // 4
#define WS_LOSSX    536584       // 8 (f64 loss patch accumulator)
#define WS_HIST     536704       // 1024 * 4         -> 540800
#define WS_PART     540800       // 512 * 8          -> 544896
#define WS_EP       802944       // 1024*128*2 f16   -> 1065088

#define MARGIN 5e-5f
#define INV2048X2 9.765625e-4f   // 2/2048, exact

typedef _Float16 half8 __attribute__((ext_vector_type(8)));
typedef _Float16 half4 __attribute__((ext_vector_type(4)));
typedef __attribute__((ext_vector_type(4))) float f32x4;
typedef __attribute__((ext_vector_type(2))) float f32x2;

// ---------------------------------------------------------------------------
// Codebook prep: se norms (f64 + f32), f16 pack Ep[k][d] = f16(-2048 * e),
// and (block 0) zeroing of hist/flagcnt/lossx (replaces hipMemsetAsync).
// ---------------------------------------------------------------------------
__global__ __launch_bounds__(256) void k_code(const float* __restrict__ emb,
                                              double* __restrict__ se64,
                                              float* __restrict__ se32,
                                              unsigned short* __restrict__ Ep,
                                              int* __restrict__ hist,
                                              int* __restrict__ flagcnt,
                                              double* __restrict__ lossx) {
    const int tid = threadIdx.x;
    if (blockIdx.x == 0) {
        reinterpret_cast<f32x4*>(hist)[tid] = (f32x4){0.f, 0.f, 0.f, 0.f};
        if (tid == 0) { *flagcnt = 0; *lossx = 0.0; }
    }
    const int sub = tid & 31;
    const int row = blockIdx.x * 8 + (tid >> 5);
    float4 v = reinterpret_cast<const float4*>(emb + ((size_t)row << 7))[sub];

    double s = (double)v.x * v.x + (double)v.y * v.y
             + (double)v.z * v.z + (double)v.w * v.w;
#pragma unroll
    for (int m = 16; m > 0; m >>= 1) s += __shfl_xor(s, m);
    if (sub == 0) { se64[row] = s; se32[row] = (float)s; }

    half4 hv;
    hv[0] = (_Float16)(-2048.0f * v.x);
    hv[1] = (_Float16)(-2048.0f * v.y);
    hv[2] = (_Float16)(-2048.0f * v.z);
    hv[3] = (_Float16)(-2048.0f * v.w);
    *reinterpret_cast<half4*>(Ep + ((size_t)row << 7) + sub * 4) = hv;
}

// ---------------------------------------------------------------------------
// FUSED: f16 MFMA distance/argmin + full output writes.
// Phase 2 order: quant+loss first (x tile still L2-warm), then the 512KB
// enc stream — all output stores nontemporal (nt) to avoid L2 thrash.
// ---------------------------------------------------------------------------
__global__ __launch_bounds__(256, 2) void k_main(
        const float* __restrict__ xg,
        const float* __restrict__ emb,
        const unsigned short* __restrict__ Ep,
        const float* __restrict__ se32,
        int* __restrict__ idx,
        int* __restrict__ flaglist,
        int* __restrict__ flagcnt,
        float* __restrict__ quant,
        float* __restrict__ enc,
        double* __restrict__ part,
        int* __restrict__ hist) {
    __shared__ char lds[65536];    // A: [0,32768) ; B: 32768 + buf*16384

    const int tid  = threadIdx.x;
    const int lane = tid & 63;
    const int w    = tid >> 6;
    const int l15  = lane & 15;
    const int quad = lane >> 4;
    const int wr   = w >> 1;
    const int wc   = w & 1;
    const int tok0 = blockIdx.x * 128;

    auto stageB = [&](int ch, int buf) {
#pragma unroll
        for (int it = 0; it < 4; ++it) {
            int L = it * 256 + w * 64 + lane;
            int c = L >> 4;
            int p = L & 15;
            const unsigned short* src =
                Ep + ((size_t)(ch * 64 + c) << 7) + ((p ^ (c & 7)) << 3);
            char* dst = lds + 32768 + buf * 16384 + (it * 256 + w * 64) * 16;
            __builtin_amdgcn_global_load_lds(
                (const __attribute__((address_space(1))) unsigned int*)src,
                (__attribute__((address_space(3))) unsigned int*)dst, 16, 0, 0);
        }
    };

    stageB(0, 0);

    // ---- stage A: 2 threads/row, f32 load -> f16 convert -> swizzled ds_write
    {
        const int r = tid >> 1;
        const int h = tid & 1;
        const float4* src =
            reinterpret_cast<const float4*>(xg + (((size_t)(tok0 + r)) << 7) + (h << 6));
#pragma unroll
        for (int p = 0; p < 8; ++p) {
            float4 f0 = src[2 * p];
            float4 f1 = src[2 * p + 1];
            half8 hv;
            hv[0] = (_Float16)f0.x; hv[1] = (_Float16)f0.y;
            hv[2] = (_Float16)f0.z; hv[3] = (_Float16)f0.w;
            hv[4] = (_Float16)f1.x; hv[5] = (_Float16)f1.y;
            hv[6] = (_Float16)f1.z; hv[7] = (_Float16)f1.w;
            int b = (h << 3) + p;
            int slot = (r << 4) + (b ^ (r & 7));
            *reinterpret_cast<half8*>(lds + slot * 16) = hv;
        }
    }
    __syncthreads();

    // ---- preload all A fragments into registers
    half8 av[4][4];
#pragma unroll
    for (int ti = 0; ti < 4; ++ti)
#pragma unroll
        for (int ks = 0; ks < 4; ++ks) {
            int m = wr * 64 + ti * 16 + l15;
            av[ti][ks] = *reinterpret_cast<const half8*>(
                lds + ((m << 4) + ((ks * 4 + quad) ^ (m & 7))) * 16);
        }

    float v1[16], v2[16];
    int   i1[16];
#pragma unroll
    for (int s = 0; s < 16; ++s) { v1[s] = 3.0e38f; v2[s] = 3.0e38f; i1[s] = 0; }

    for (int ch = 0; ch < 16; ++ch) {
        if (ch + 1 < 16) stageB(ch + 1, (ch + 1) & 1);

        const char* Bb = lds + 32768 + (ch & 1) * 16384;
        f32x4 acc[4][2];
#pragma unroll
        for (int ti = 0; ti < 4; ++ti) {
            acc[ti][0] = (f32x4){0.f, 0.f, 0.f, 0.f};
            acc[ti][1] = (f32x4){0.f, 0.f, 0.f, 0.f};
        }

#pragma unroll
        for (int ks = 0; ks < 4; ++ks) {
            int c0 = wc * 32 + l15;
            int c1 = c0 + 16;
            half8 bv0 = *reinterpret_cast<const half8*>(
                Bb + ((c0 << 4) + ((ks * 4 + quad) ^ (c0 & 7))) * 16);
            half8 bv1 = *reinterpret_cast<const half8*>(
                Bb + ((c1 << 4) + ((ks * 4 + quad) ^ (c1 & 7))) * 16);
#pragma unroll
            for (int ti = 0; ti < 4; ++ti) {
                acc[ti][0] = __builtin_amdgcn_mfma_f32_16x16x32_f16(
                    av[ti][ks], bv0, acc[ti][0], 0, 0, 0);
                acc[ti][1] = __builtin_amdgcn_mfma_f32_16x16x32_f16(
                    av[ti][ks], bv1, acc[ti][1], 0, 0, 0);
            }
        }

#pragma unroll
        for (int tj = 0; tj < 2; ++tj) {
            int cg = ch * 64 + wc * 32 + tj * 16 + l15;
            float se = se32[cg];
#pragma unroll
            for (int ti = 0; ti < 4; ++ti) {
                f32x4 A = acc[ti][tj];
#pragma unroll
                for (int rr = 0; rr < 4; ++rr) {
                    float u = fmaf(A[rr], INV2048X2, se);
                    int s = ti * 4 + rr;
                    float p1 = v1[s];
                    v2[s] = fminf(fmaxf(u, p1), v2[s]);   // med3
                    bool c = u < p1;
                    v1[s] = c ? u : p1;
                    i1[s] = c ? cg : i1[s];
                }
            }
        }
        __syncthreads();
    }

    // ---- cross-lane/wave argmin reduction
    float* v1L = reinterpret_cast<float*>(lds);            // 16KB
    float* v2L = reinterpret_cast<float*>(lds + 16384);    // 16KB
    int*   i1L = reinterpret_cast<int*>(lds + 32768);      // 16KB
    int*   kidxL = reinterpret_cast<int*>(lds + 49152);    // 512B
#pragma unroll
    for (int ti = 0; ti < 4; ++ti)
#pragma unroll
        for (int rr = 0; rr < 4; ++rr) {
            int t_local = wr * 64 + ti * 16 + quad * 4 + rr;
            int slot = t_local * 32 + wc * 16 + l15;
            v1L[slot] = v1[ti * 4 + rr];
            v2L[slot] = v2[ti * 4 + rr];
            i1L[slot] = i1[ti * 4 + rr];
        }
    __syncthreads();

    if (tid < 128) {
        int base = tid * 32;
        float V1 = v1L[base], V2 = v2L[base];
        int I = i1L[base];
        for (int j = 1; j < 32; ++j) {
            float b1 = v1L[base + j];
            float b2 = v2L[base + j];
            int bi = i1L[base + j];
            if (b1 < V1 || (b1 == V1 && bi < I)) { V2 = fminf(V1, b2); V1 = b1; I = bi; }
            else V2 = fminf(V2, b1);
        }
        idx[tok0 + tid] = I;
        kidxL[tid] = I;
        if (V2 - V1 < MARGIN) {
            int p = atomicAdd(flagcnt, 1);
            flaglist[p] = tok0 + tid;
        }
    }
    __syncthreads();

    // ---- phase 2a: hist atomics (latency overlaps the stores below)
    if (tid < 128) atomicAdd(&hist[kidxL[tid]], 1);

    // ---- phase 2b: quant rows + f64 loss partial FIRST (x tile L2-warm),
    //      float4 loads, nt float4 stores (dword alignment suffices).
    double lacc = 0.0;
    {
        const int c4 = (tid & 31) * 4;           // float col within row
        const int tsub = tid >> 5;               // token sub-index 0..7
        for (int it = 0; it < 16; ++it) {
            int t = it * 8 + tsub;
            int k = kidxL[t];
            size_t go = (((size_t)(tok0 + t)) << 7) + c4;
            float4 xv = *reinterpret_cast<const float4*>(xg + go);
            float4 ev = *reinterpret_cast<const float4*>(emb + (((size_t)k) << 7) + c4);
            float d0 = ev.x - xv.x;
            float d1 = ev.y - xv.y;
            float d2 = ev.z - xv.z;
            float d3 = ev.w - xv.w;
            f32x4 q = {xv.x + d0, xv.y + d1, xv.z + d2, xv.w + d3};
            __builtin_nontemporal_store(q, reinterpret_cast<f32x4*>(quant + go));
            lacc += (double)(d0 * d0) + (double)(d1 * d1)
                  + (double)(d2 * d2) + (double)(d3 * d3);
        }
    }
    for (int off = 32; off > 0; off >>= 1) lacc += __shfl_down(lacc, off);
    double* wsum = reinterpret_cast<double*>(lds + 49664);
    if (lane == 0) wsum[w] = lacc;

    // ---- phase 2c: enc rows — 1KB contiguous per wave-instr, nt dwordx4
    {
        const int c0 = tid * 4;
        for (int t = 0; t < 128; ++t) {
            int k = kidxL[t];
            f32x4 z;
            z[0] = (c0 == k)     ? 1.0f : 0.0f;
            z[1] = (c0 + 1 == k) ? 1.0f : 0.0f;
            z[2] = (c0 + 2 == k) ? 1.0f : 0.0f;
            z[3] = (c0 + 3 == k) ? 1.0f : 0.0f;
            __builtin_nontemporal_store(
                z, reinterpret_cast<f32x4*>(enc + (((size_t)(tok0 + t)) << 10) + c0));
        }
    }
    __syncthreads();
    if (tid == 0) part[blockIdx.x] = wsum[0] + wsum[1] + wsum[2] + wsum[3];
}

// ---------------------------------------------------------------------------
// fp64 rescan of near-tie tokens; patches outputs only when idx changes.
// ---------------------------------------------------------------------------
__global__ __launch_bounds__(256) void k_refine(const float* __restrict__ xg,
                                                const float* __restrict__ emb,
                                                const double* __restrict__ se64,
                                                const int* __restrict__ flaglist,
                                                const int* __restrict__ flagcnt,
                                                int* __restrict__ idx,
                                                float* __restrict__ quant,
                                                float* __restrict__ enc,
                                                int* __restrict__ hist,
                                                double* __restrict__ lossx) {
    __shared__ float xsh[DIM];
    __shared__ double rv[256];
    __shared__ int ri[256];
    const int tid = threadIdx.x;
    const int cnt = *flagcnt;

    for (int f = blockIdx.x; f < cnt; f += gridDim.x) {
        int t = flaglist[f];
        __syncthreads();
        if (tid < DIM) xsh[tid] = xg[(size_t)t * DIM + tid];
        __syncthreads();

        double best = 1.0e300;
        int bi = 0;
#pragma unroll
        for (int j = 0; j < 4; ++j) {
            int k = tid * 4 + j;
            const float* er = emb + (size_t)k * DIM;
            double m = 0.0;
            for (int d = 0; d < DIM; ++d)
                m = fma((double)xsh[d], (double)er[d], m);
            double u = se64[k] - 2.0 * m;
            if (u < best) { best = u; bi = k; }
        }
        rv[tid] = best;
        ri[tid] = bi;
        __syncthreads();
        for (int s = 128; s > 0; s >>= 1) {
            if (tid < s) {
                if (rv[tid + s] < rv[tid] ||
                    (rv[tid + s] == rv[tid] && ri[tid + s] < ri[tid])) {
                    rv[tid] = rv[tid + s];
                    ri[tid] = ri[tid + s];
                }
            }
            __syncthreads();
        }
        int newk = ri[0];
        int oldk = idx[t];
        if (newk != oldk) {
            double delta = 0.0;
            if (tid < DIM) {
                float xd = xsh[tid];
                float en = emb[((size_t)newk << 7) + tid];
                float eo = emb[((size_t)oldk << 7) + tid];
                float dn = en - xd;
                float dl = eo - xd;
                quant[((size_t)t << 7) + tid] = xd + dn;
                delta = (double)(dn * dn) - (double)(dl * dl);
            }
            rv[tid] = delta;
            __syncthreads();
            for (int s = 128; s > 0; s >>= 1) {
                if (tid < s) rv[tid] += rv[tid + s];
                __syncthreads();
            }
            if (tid == 0) {
                atomicAdd(lossx, rv[0]);
                enc[((size_t)t << 10) + oldk] = 0.0f;
                enc[((size_t)t << 10) + newk] = 1.0f;
                atomicAdd(&hist[oldk], -1);
                atomicAdd(&hist[newk], 1);
                idx[t] = newk;
            }
        }
        __syncthreads();
    }
}

// ---------------------------------------------------------------------------
__global__ __launch_bounds__(256) void k_final(const double* __restrict__ part,
                                               const double* __restrict__ lossx,
                                               const int* __restrict__ hist,
                                               float* __restrict__ out_loss,
                                               float* __restrict__ out_perp) {
    __shared__ double red[256];
    const int tid = threadIdx.x;

    double s = 0.0;
    for (int i = tid; i < 512; i += 256) s += part[i];
    red[tid] = s;
    __syncthreads();
    for (int st = 128; st > 0; st >>= 1) {
        if (tid < st) red[tid] += red[tid + st];
        __syncthreads();
    }
    double loss = (red[0] + *lossx) / 8388608.0;
    __syncthreads();

    double e = 0.0;
    for (int b = tid; b < KCODE; b += 256) {
        double p = (double)hist[b] * (1.0 / 65536.0);
        e += p * log(p + 1e-10);
    }
    red[tid] = e;
    __syncthreads();
    for (int st = 128; st > 0; st >>= 1) {
        if (tid < st) red[tid] += red[tid + st];
        __syncthreads();
    }
    if (tid == 0) {
        *out_loss = (float)loss;
        *out_perp = (float)exp(-red[0]);
    }
}

// ---------------------------------------------------------------------------
extern "C" void kernel_launch(void* const* d_in, const int* in_sizes, int n_in,
                              void* d_out, int out_size, void* d_ws, size_t ws_size,
                              hipStream_t stream) {
    const float* x   = (const float*)d_in[0];
    const float* emb = (const float*)d_in[1];
    float* out = (float*)d_out;
    char*  ws  = (char*)d_ws;

    double* se64   = (double*)(ws + WS_SE64);
    float*  se32   = (float*)(ws + WS_SE32);
    int*    idx    = (int*)(ws + WS_IDX);
    int*    flglst = (int*)(ws + WS_FLAGLIST);
    int*    flgcnt = (int*)(ws + WS_FLAGCNT);
    double* lossx  = (double*)(ws + WS_LOSSX);
    int*    hist   = (int*)(ws + WS_HIST);
    double* part   = (double*)(ws + WS_PART);
    unsigned short* Ep = (unsigned short*)(ws + WS_EP);

    float* quant = out + OUT_QUANT_OFF;
    float* enc   = out + OUT_ENC_OFF;

    k_code <<<KCODE / 8, 256, 0, stream>>>(emb, se64, se32, Ep, hist, flgcnt, lossx);
    k_main <<<N_TOK / 128, 256, 0, stream>>>(x, emb, Ep, se32, idx, flglst, flgcnt,
                                             quant, enc, part, hist);
    k_refine<<<256, 256, 0, stream>>>(x, emb, se64, flglst, flgcnt, idx,
                                      quant, enc, hist, lossx);
    k_final<<<1, 256, 0, stream>>>(part, lossx, hist, out, out + OUT_PERP_OFF);
}

// Round 6
// 448.772 us; speedup vs baseline: 1.0004x; 1.0004x over previous
//
#include <hip/hip_runtime.h>
#include <math.h>

#define N_TOK   65536
#define DIM     128
#define KCODE   1024

// ---- d_out element offsets ----
#define OUT_QUANT_OFF 1
#define OUT_PERP_OFF  8388609
#define OUT_ENC_OFF   8388610

// ---- workspace byte offsets ----
#define WS_SE64     0            // 1024 * 8
#define WS_SE32     8192         // 1024 * 4
#define WS_IDX      12288        // 65536 * 4        -> 274432
#define WS_FLAGLIST 274432       // 65536 * 4        -> 536576
#define WS_FLAGCNT  536576       // 4
#define WS_LOSSX    536584       // 8 (f64 loss patch accumulator)
#define WS_DONE     536592       // 4 (refine done-counter)
#define WS_HIST     536704       // 1024 * 4         -> 540800
#define WS_PART     540800       // 512 * 8          -> 544896
#define WS_EP       802944       // 1024*128*2 f16   -> 1065088

#define MARGIN 5e-5f
#define INV2048X2 9.765625e-4f   // 2/2048, exact

typedef _Float16 half8 __attribute__((ext_vector_type(8)));
typedef _Float16 half4 __attribute__((ext_vector_type(4)));
typedef __attribute__((ext_vector_type(4))) float f32x4;

// ---------------------------------------------------------------------------
// Codebook prep: se norms (f64 + f32), f16 pack Ep[k][d] = f16(-2048 * e),
// and (block 0) zeroing of hist/flagcnt/lossx/done.
// ---------------------------------------------------------------------------
__global__ __launch_bounds__(256) void k_code(const float* __restrict__ emb,
                                              double* __restrict__ se64,
                                              float* __restrict__ se32,
                                              unsigned short* __restrict__ Ep,
                                              int* __restrict__ hist,
                                              int* __restrict__ flagcnt,
                                              double* __restrict__ lossx,
                                              int* __restrict__ done) {
    const int tid = threadIdx.x;
    if (blockIdx.x == 0) {
        reinterpret_cast<f32x4*>(hist)[tid] = (f32x4){0.f, 0.f, 0.f, 0.f};
        if (tid == 0) { *flagcnt = 0; *lossx = 0.0; *done = 0; }
    }
    const int sub = tid & 31;
    const int row = blockIdx.x * 8 + (tid >> 5);
    float4 v = reinterpret_cast<const float4*>(emb + ((size_t)row << 7))[sub];

    double s = (double)v.x * v.x + (double)v.y * v.y
             + (double)v.z * v.z + (double)v.w * v.w;
#pragma unroll
    for (int m = 16; m > 0; m >>= 1) s += __shfl_xor(s, m);
    if (sub == 0) { se64[row] = s; se32[row] = (float)s; }

    half4 hv;
    hv[0] = (_Float16)(-2048.0f * v.x);
    hv[1] = (_Float16)(-2048.0f * v.y);
    hv[2] = (_Float16)(-2048.0f * v.z);
    hv[3] = (_Float16)(-2048.0f * v.w);
    *reinterpret_cast<half4*>(Ep + ((size_t)row << 7) + sub * 4) = hv;
}

// ---------------------------------------------------------------------------
// FUSED: f16 MFMA distance/argmin + full output writes.
// Phase 2 order: quant+loss first (x tile L2-warm), then the 512KB enc
// stream. Regular (cached) stores — NT regressed (R5: partial-line HBM
// writes on the 8-mod-16-aligned enc stream).
// ---------------------------------------------------------------------------
__global__ __launch_bounds__(256, 2) void k_main(
        const float* __restrict__ xg,
        const float* __restrict__ emb,
        const unsigned short* __restrict__ Ep,
        const float* __restrict__ se32,
        int* __restrict__ idx,
        int* __restrict__ flaglist,
        int* __restrict__ flagcnt,
        float* __restrict__ quant,
        float* __restrict__ enc,
        double* __restrict__ part,
        int* __restrict__ hist) {
    __shared__ char lds[65536];    // A: [0,32768) ; B: 32768 + buf*16384

    const int tid  = threadIdx.x;
    const int lane = tid & 63;
    const int w    = tid >> 6;
    const int l15  = lane & 15;
    const int quad = lane >> 4;
    const int wr   = w >> 1;
    const int wc   = w & 1;
    const int tok0 = blockIdx.x * 128;

    auto stageB = [&](int ch, int buf) {
#pragma unroll
        for (int it = 0; it < 4; ++it) {
            int L = it * 256 + w * 64 + lane;
            int c = L >> 4;
            int p = L & 15;
            const unsigned short* src =
                Ep + ((size_t)(ch * 64 + c) << 7) + ((p ^ (c & 7)) << 3);
            char* dst = lds + 32768 + buf * 16384 + (it * 256 + w * 64) * 16;
            __builtin_amdgcn_global_load_lds(
                (const __attribute__((address_space(1))) unsigned int*)src,
                (__attribute__((address_space(3))) unsigned int*)dst, 16, 0, 0);
        }
    };

    stageB(0, 0);

    // ---- stage A: 2 threads/row, f32 load -> f16 convert -> swizzled ds_write
    {
        const int r = tid >> 1;
        const int h = tid & 1;
        const float4* src =
            reinterpret_cast<const float4*>(xg + (((size_t)(tok0 + r)) << 7) + (h << 6));
#pragma unroll
        for (int p = 0; p < 8; ++p) {
            float4 f0 = src[2 * p];
            float4 f1 = src[2 * p + 1];
            half8 hv;
            hv[0] = (_Float16)f0.x; hv[1] = (_Float16)f0.y;
            hv[2] = (_Float16)f0.z; hv[3] = (_Float16)f0.w;
            hv[4] = (_Float16)f1.x; hv[5] = (_Float16)f1.y;
            hv[6] = (_Float16)f1.z; hv[7] = (_Float16)f1.w;
            int b = (h << 3) + p;
            int slot = (r << 4) + (b ^ (r & 7));
            *reinterpret_cast<half8*>(lds + slot * 16) = hv;
        }
    }
    __syncthreads();

    // ---- preload all A fragments into registers
    half8 av[4][4];
#pragma unroll
    for (int ti = 0; ti < 4; ++ti)
#pragma unroll
        for (int ks = 0; ks < 4; ++ks) {
            int m = wr * 64 + ti * 16 + l15;
            av[ti][ks] = *reinterpret_cast<const half8*>(
                lds + ((m << 4) + ((ks * 4 + quad) ^ (m & 7))) * 16);
        }

    float v1[16], v2[16];
    int   i1[16];
#pragma unroll
    for (int s = 0; s < 16; ++s) { v1[s] = 3.0e38f; v2[s] = 3.0e38f; i1[s] = 0; }

    for (int ch = 0; ch < 16; ++ch) {
        if (ch + 1 < 16) stageB(ch + 1, (ch + 1) & 1);

        const char* Bb = lds + 32768 + (ch & 1) * 16384;
        f32x4 acc[4][2];
#pragma unroll
        for (int ti = 0; ti < 4; ++ti) {
            acc[ti][0] = (f32x4){0.f, 0.f, 0.f, 0.f};
            acc[ti][1] = (f32x4){0.f, 0.f, 0.f, 0.f};
        }

#pragma unroll
        for (int ks = 0; ks < 4; ++ks) {
            int c0 = wc * 32 + l15;
            int c1 = c0 + 16;
            half8 bv0 = *reinterpret_cast<const half8*>(
                Bb + ((c0 << 4) + ((ks * 4 + quad) ^ (c0 & 7))) * 16);
            half8 bv1 = *reinterpret_cast<const half8*>(
                Bb + ((c1 << 4) + ((ks * 4 + quad) ^ (c1 & 7))) * 16);
#pragma unroll
            for (int ti = 0; ti < 4; ++ti) {
                acc[ti][0] = __builtin_amdgcn_mfma_f32_16x16x32_f16(
                    av[ti][ks], bv0, acc[ti][0], 0, 0, 0);
                acc[ti][1] = __builtin_amdgcn_mfma_f32_16x16x32_f16(
                    av[ti][ks], bv1, acc[ti][1], 0, 0, 0);
            }
        }

#pragma unroll
        for (int tj = 0; tj < 2; ++tj) {
            int cg = ch * 64 + wc * 32 + tj * 16 + l15;
            float se = se32[cg];
#pragma unroll
            for (int ti = 0; ti < 4; ++ti) {
                f32x4 A = acc[ti][tj];
#pragma unroll
                for (int rr = 0; rr < 4; ++rr) {
                    float u = fmaf(A[rr], INV2048X2, se);
                    int s = ti * 4 + rr;
                    float p1 = v1[s];
                    v2[s] = fminf(fmaxf(u, p1), v2[s]);   // med3
                    bool c = u < p1;
                    v1[s] = c ? u : p1;
                    i1[s] = c ? cg : i1[s];
                }
            }
        }
        __syncthreads();
    }

    // ---- cross-lane/wave argmin reduction
    float* v1L = reinterpret_cast<float*>(lds);            // 16KB
    float* v2L = reinterpret_cast<float*>(lds + 16384);    // 16KB
    int*   i1L = reinterpret_cast<int*>(lds + 32768);      // 16KB
    int*   kidxL = reinterpret_cast<int*>(lds + 49152);    // 512B
#pragma unroll
    for (int ti = 0; ti < 4; ++ti)
#pragma unroll
        for (int rr = 0; rr < 4; ++rr) {
            int t_local = wr * 64 + ti * 16 + quad * 4 + rr;
            int slot = t_local * 32 + wc * 16 + l15;
            v1L[slot] = v1[ti * 4 + rr];
            v2L[slot] = v2[ti * 4 + rr];
            i1L[slot] = i1[ti * 4 + rr];
        }
    __syncthreads();

    if (tid < 128) {
        int base = tid * 32;
        float V1 = v1L[base], V2 = v2L[base];
        int I = i1L[base];
        for (int j = 1; j < 32; ++j) {
            float b1 = v1L[base + j];
            float b2 = v2L[base + j];
            int bi = i1L[base + j];
            if (b1 < V1 || (b1 == V1 && bi < I)) { V2 = fminf(V1, b2); V1 = b1; I = bi; }
            else V2 = fminf(V2, b1);
        }
        idx[tok0 + tid] = I;
        kidxL[tid] = I;
        if (V2 - V1 < MARGIN) {
            int p = atomicAdd(flagcnt, 1);
            flaglist[p] = tok0 + tid;
        }
    }
    __syncthreads();

    // ---- phase 2a: hist atomics (latency overlaps the stores below)
    if (tid < 128) atomicAdd(&hist[kidxL[tid]], 1);

    // ---- phase 2b: quant rows + f64 loss partial (x tile L2-warm),
    //      float4 loads + float4 stores.
    double lacc = 0.0;
    {
        const int c4 = (tid & 31) * 4;           // float col within row
        const int tsub = tid >> 5;               // token sub-index 0..7
        for (int it = 0; it < 16; ++it) {
            int t = it * 8 + tsub;
            int k = kidxL[t];
            size_t go = (((size_t)(tok0 + t)) << 7) + c4;
            float4 xv = *reinterpret_cast<const float4*>(xg + go);
            float4 ev = *reinterpret_cast<const float4*>(emb + (((size_t)k) << 7) + c4);
            float d0 = ev.x - xv.x;
            float d1 = ev.y - xv.y;
            float d2 = ev.z - xv.z;
            float d3 = ev.w - xv.w;
            f32x4 q = {xv.x + d0, xv.y + d1, xv.z + d2, xv.w + d3};
            *reinterpret_cast<f32x4*>(quant + go) = q;
            lacc += (double)(d0 * d0) + (double)(d1 * d1)
                  + (double)(d2 * d2) + (double)(d3 * d3);
        }
    }
    for (int off = 32; off > 0; off >>= 1) lacc += __shfl_down(lacc, off);
    double* wsum = reinterpret_cast<double*>(lds + 49664);
    if (lane == 0) wsum[w] = lacc;

    // ---- phase 2c: enc rows — 1KB contiguous per wave-instr, dwordx4
    {
        const int c0 = tid * 4;
        for (int t = 0; t < 128; ++t) {
            int k = kidxL[t];
            f32x4 z;
            z[0] = (c0 == k)     ? 1.0f : 0.0f;
            z[1] = (c0 + 1 == k) ? 1.0f : 0.0f;
            z[2] = (c0 + 2 == k) ? 1.0f : 0.0f;
            z[3] = (c0 + 3 == k) ? 1.0f : 0.0f;
            *reinterpret_cast<f32x4*>(enc + (((size_t)(tok0 + t)) << 10) + c0) = z;
        }
    }
    __syncthreads();
    if (tid == 0) part[blockIdx.x] = wsum[0] + wsum[1] + wsum[2] + wsum[3];
}

// ---------------------------------------------------------------------------
// fp64 rescan of near-tie tokens; patches outputs only when idx changes.
// Last block to finish also computes the final loss/perplexity scalars.
// ---------------------------------------------------------------------------
__global__ __launch_bounds__(256) void k_refine(const float* __restrict__ xg,
                                                const float* __restrict__ emb,
                                                const double* __restrict__ se64,
                                                const int* __restrict__ flaglist,
                                                const int* __restrict__ flagcnt,
                                                int* __restrict__ idx,
                                                float* __restrict__ quant,
                                                float* __restrict__ enc,
                                                int* __restrict__ hist,
                                                double* __restrict__ lossx,
                                                int* __restrict__ done,
                                                const double* __restrict__ part,
                                                float* __restrict__ out_loss,
                                                float* __restrict__ out_perp) {
    __shared__ float xsh[DIM];
    __shared__ double rv[256];
    __shared__ int ri[256];
    __shared__ int amLast;
    const int tid = threadIdx.x;
    const int cnt = *flagcnt;

    for (int f = blockIdx.x; f < cnt; f += gridDim.x) {
        int t = flaglist[f];
        __syncthreads();
        if (tid < DIM) xsh[tid] = xg[(size_t)t * DIM + tid];
        __syncthreads();

        double best = 1.0e300;
        int bi = 0;
#pragma unroll
        for (int j = 0; j < 4; ++j) {
            int k = tid * 4 + j;
            const float* er = emb + (size_t)k * DIM;
            double m = 0.0;
            for (int d = 0; d < DIM; ++d)
                m = fma((double)xsh[d], (double)er[d], m);
            double u = se64[k] - 2.0 * m;
            if (u < best) { best = u; bi = k; }
        }
        rv[tid] = best;
        ri[tid] = bi;
        __syncthreads();
        for (int s = 128; s > 0; s >>= 1) {
            if (tid < s) {
                if (rv[tid + s] < rv[tid] ||
                    (rv[tid + s] == rv[tid] && ri[tid + s] < ri[tid])) {
                    rv[tid] = rv[tid + s];
                    ri[tid] = ri[tid + s];
                }
            }
            __syncthreads();
        }
        int newk = ri[0];
        int oldk = idx[t];
        if (newk != oldk) {
            double delta = 0.0;
            if (tid < DIM) {
                float xd = xsh[tid];
                float en = emb[((size_t)newk << 7) + tid];
                float eo = emb[((size_t)oldk << 7) + tid];
                float dn = en - xd;
                float dl = eo - xd;
                quant[((size_t)t << 7) + tid] = xd + dn;
                delta = (double)(dn * dn) - (double)(dl * dl);
            }
            rv[tid] = delta;
            __syncthreads();
            for (int s = 128; s > 0; s >>= 1) {
                if (tid < s) rv[tid] += rv[tid + s];
                __syncthreads();
            }
            if (tid == 0) {
                atomicAdd(lossx, rv[0]);
                enc[((size_t)t << 10) + oldk] = 0.0f;
                enc[((size_t)t << 10) + newk] = 1.0f;
                atomicAdd(&hist[oldk], -1);
                atomicAdd(&hist[newk], 1);
                idx[t] = newk;
            }
        }
        __syncthreads();
    }

    // ---- last-block final reduction (replaces k_final launch)
    __threadfence();
    if (tid == 0) amLast = (atomicAdd(done, 1) == gridDim.x - 1);
    __syncthreads();
    if (!amLast) return;
    __threadfence();   // acquire: see all blocks' lossx/hist atomics

    double s = 0.0;
    for (int i = tid; i < 512; i += 256) s += part[i];
    rv[tid] = s;
    __syncthreads();
    for (int st = 128; st > 0; st >>= 1) {
        if (tid < st) rv[tid] += rv[tid + st];
        __syncthreads();
    }
    double loss = (rv[0] + *lossx) / 8388608.0;
    __syncthreads();

    double e = 0.0;
    for (int b = tid; b < KCODE; b += 256) {
        double p = (double)hist[b] * (1.0 / 65536.0);
        e += p * log(p + 1e-10);
    }
    rv[tid] = e;
    __syncthreads();
    for (int st = 128; st > 0; st >>= 1) {
        if (tid < st) rv[tid] += rv[tid + st];
        __syncthreads();
    }
    if (tid == 0) {
        *out_loss = (float)loss;
        *out_perp = (float)exp(-rv[0]);
    }
}

// ---------------------------------------------------------------------------
extern "C" void kernel_launch(void* const* d_in, const int* in_sizes, int n_in,
                              void* d_out, int out_size, void* d_ws, size_t ws_size,
                              hipStream_t stream) {
    const float* x   = (const float*)d_in[0];
    const float* emb = (const float*)d_in[1];
    float* out = (float*)d_out;
    char*  ws  = (char*)d_ws;

    double* se64   = (double*)(ws + WS_SE64);
    float*  se32   = (float*)(ws + WS_SE32);
    int*    idx    = (int*)(ws + WS_IDX);
    int*    flglst = (int*)(ws + WS_FLAGLIST);
    int*    flgcnt = (int*)(ws + WS_FLAGCNT);
    double* lossx  = (double*)(ws + WS_LOSSX);
    int*    done   = (int*)(ws + WS_DONE);
    int*    hist   = (int*)(ws + WS_HIST);
    double* part   = (double*)(ws + WS_PART);
    unsigned short* Ep = (unsigned short*)(ws + WS_EP);

    float* quant = out + OUT_QUANT_OFF;
    float* enc   = out + OUT_ENC_OFF;

    k_code <<<KCODE / 8, 256, 0, stream>>>(emb, se64, se32, Ep, hist, flgcnt,
                                           lossx, done);
    k_main <<<N_TOK / 128, 256, 0, stream>>>(x, emb, Ep, se32, idx, flglst, flgcnt,
                                             quant, enc, part, hist);
    k_refine<<<256, 256, 0, stream>>>(x, emb, se64, flglst, flgcnt, idx,
                                      quant, enc, hist, lossx, done, part,
                                      out, out + OUT_PERP_OFF);
}